// Round 3
// baseline (5239.094 us; speedup 1.0000x reference)
//
#include <hip/hip_runtime.h>

#define LSTM_B 512
#define LSTM_L 1000
#define LSTM_H 128
#define LSTM_G 512  // 4*H

typedef _Float16 h2v __attribute__((ext_vector_type(2)));

__device__ __forceinline__ float sigmoid_f(float x) {
  return __builtin_amdgcn_rcpf(1.0f + __builtin_amdgcn_exp2f(-1.4426950408889634f * x));
}
__device__ __forceinline__ float tanh_f(float x) {
  // tanh(x) = 1 - 2/(exp2(2x*log2e)+1); saturates cleanly via exp2->inf / ->0
  return 1.0f - 2.0f * __builtin_amdgcn_rcpf(1.0f + __builtin_amdgcn_exp2f(2.8853900817779268f * x));
}

#if defined(__has_builtin)
#if __has_builtin(__builtin_amdgcn_fdot2)
#define HAVE_FDOT2 1
#endif
#endif

__device__ __forceinline__ float dot2acc(h2v h, h2v w, float acc) {
#ifdef HAVE_FDOT2
  return __builtin_amdgcn_fdot2(h, w, acc, false);
#else
  return acc + (float)h.x * (float)w.x + (float)h.y * (float)w.y;
#endif
}

// One block = one CU owns 2 batch rows for the whole sequence.
// Thread j holds f16 copies of gate-row j of w_hh1, w_ih2, w_hh2 in VGPRs
// (3 x 64 packed f16x2 = 192 VGPRs). h vectors are exchanged through LDS as
// packed f16x2 dwords (lane l holds pair l) and broadcast via v_readlane.
//
// NO __launch_bounds__: its lowering emits a min-only amdgpu-waves-per-eu
// that overrides the explicit attribute and the allocator then targets
// 4 waves/EU -> 128-VGPR cap -> 192-VGPR weight arrays spill (rounds 1-2:
// VGPR_Count=128, WRITE_SIZE=74.7MB vs 2MB of real output). Pinning
// waves_per_eu to exactly 2 gives the 256-VGPR budget this design needs.
__global__
__attribute__((amdgpu_flat_work_group_size(512, 512)))
__attribute__((amdgpu_waves_per_eu(2, 2)))
void lstm_fused(
    const float* __restrict__ x,
    const float* __restrict__ w_ih1,
    const float* __restrict__ w_hh1,
    const float* __restrict__ b_ih1,
    const float* __restrict__ b_hh1,
    const float* __restrict__ w_ih2,
    const float* __restrict__ w_hh2,
    const float* __restrict__ b_ih2,
    const float* __restrict__ b_hh2,
    const float* __restrict__ w_lin,
    const float* __restrict__ b_lin,
    float* __restrict__ out)
{
  __shared__ float xlds[2 * LSTM_L];        // x for the block's 2 rows
  __shared__ float actbuf[2][LSTM_G];       // activated gates, [row][gate]
  __shared__ unsigned hbuf1[2][LSTM_H / 2]; // h1 packed f16x2, [row][pair]
  __shared__ unsigned hbuf2[2][LSTM_H / 2]; // h2 packed f16x2
  __shared__ float redbuf[2];               // output partial per row

  const int tid  = threadIdx.x;
  const int lane = tid & 63;
  const int r0   = blockIdx.x * 2;

  // stage x rows (contiguous: rows r0, r0+1) into LDS, coalesced
  for (int i = tid; i < 2 * LSTM_L; i += 512) xlds[i] = x[r0 * LSTM_L + i];

  // per-thread weight rows -> registers (f16x2 packed)
  h2v w1[64], w2i[64], w2h[64];
  {
    const float2* pa = (const float2*)(w_hh1 + tid * LSTM_H);
    const float2* pb = (const float2*)(w_ih2 + tid * LSTM_H);
    const float2* pc = (const float2*)(w_hh2 + tid * LSTM_H);
#pragma unroll
    for (int i = 0; i < 64; ++i) {
      float2 fa = pa[i]; w1[i]  = h2v{(_Float16)fa.x, (_Float16)fa.y};
      float2 fb = pb[i]; w2i[i] = h2v{(_Float16)fb.x, (_Float16)fb.y};
      float2 fc = pc[i]; w2h[i] = h2v{(_Float16)fc.x, (_Float16)fc.y};
    }
  }
  const float wx  = w_ih1[tid];
  const float bb1 = b_ih1[tid] + b_hh1[tid];
  const float bb2 = b_ih2[tid] + b_hh2[tid];
  const bool  isG = (tid >= 2 * LSTM_H) && (tid < 3 * LSTM_H);  // tanh gate

  // cell-state ownership:
  //  tid <  128           : h1/c1 elems {2k,2k+1}, row = tid>>6, k = tid&63
  //  128 <= tid < 256     : h2/c2 elems {2k,2k+1}, row = (tid>>6)&1, k = tid&63
  float cs_lo = 0.f, cs_hi = 0.f;
  const int kk = tid & 63;
  float wl_lo = 0.f, wl_hi = 0.f;
  if (tid >= 128 && tid < 256) { wl_lo = w_lin[2 * kk]; wl_hi = w_lin[2 * kk + 1]; }
  const float blv = b_lin[0];

  // carried partial dot products (h == 0 initially -> partials are 0)
  float g1pa = 0.f, g1pb = 0.f;  // w_hh1 @ h1   (rows a=r0, b=r0+1)
  float p2ha = 0.f, p2hb = 0.f;  // w_hh2 @ h2

  __syncthreads();

  for (int t = 0; t < LSTM_L; ++t) {
    // ---- phase 1: finish layer-1 gates, activate
    {
      float g1a = g1pa + wx * xlds[t]          + bb1;
      float g1b = g1pb + wx * xlds[LSTM_L + t] + bb1;
      actbuf[0][tid] = isG ? tanh_f(g1a) : sigmoid_f(g1a);
      actbuf[1][tid] = isG ? tanh_f(g1b) : sigmoid_f(g1b);
    }
    __syncthreads();

    // ---- phase 2: c1/h1 update (threads 0..127; one row per wave)
    if (tid < 128) {
      const int row = tid >> 6;
      const int e   = kk * 2;
      const float* ab = actbuf[row];
      float i0 = ab[e],       i1 = ab[e + 1];
      float f0 = ab[128 + e], f1 = ab[128 + e + 1];
      float g0 = ab[256 + e], g1 = ab[256 + e + 1];
      float o0 = ab[384 + e], o1 = ab[384 + e + 1];
      cs_lo = f0 * cs_lo + i0 * g0;
      cs_hi = f1 * cs_hi + i1 * g1;
      h2v hp = h2v{(_Float16)(o0 * tanh_f(cs_lo)), (_Float16)(o1 * tanh_f(cs_hi))};
      hbuf1[row][kk] = __builtin_bit_cast(unsigned, hp);
    }
    __syncthreads();

    // ---- phase 3: w_ih2 @ h1new (this step)  +  w_hh1 @ h1new (next step)
    {
      int hv1a = (int)hbuf1[0][lane];
      int hv1b = (int)hbuf1[1][lane];
      float g2a = p2ha + bb2;
      float g2b = p2hb + bb2;
      g1pa = 0.f; g1pb = 0.f;
#pragma unroll
      for (int i = 0; i < 64; ++i) {
        int qa = __builtin_amdgcn_readlane(hv1a, i);
        int qb = __builtin_amdgcn_readlane(hv1b, i);
        h2v ha = __builtin_bit_cast(h2v, qa);
        h2v hb = __builtin_bit_cast(h2v, qb);
        g2a  = dot2acc(ha, w2i[i], g2a);
        g2b  = dot2acc(hb, w2i[i], g2b);
        g1pa = dot2acc(ha, w1[i],  g1pa);
        g1pb = dot2acc(hb, w1[i],  g1pb);
      }
      actbuf[0][tid] = isG ? tanh_f(g2a) : sigmoid_f(g2a);
      actbuf[1][tid] = isG ? tanh_f(g2b) : sigmoid_f(g2b);
    }
    __syncthreads();

    // ---- phase 4: c2/h2 update (threads 128..255) + output partial
    if (tid >= 128 && tid < 256) {
      const int row = (tid >> 6) & 1;
      const int e   = kk * 2;
      const float* ab = actbuf[row];
      float i0 = ab[e],       i1 = ab[e + 1];
      float f0 = ab[128 + e], f1 = ab[128 + e + 1];
      float g0 = ab[256 + e], g1 = ab[256 + e + 1];
      float o0 = ab[384 + e], o1 = ab[384 + e + 1];
      cs_lo = f0 * cs_lo + i0 * g0;
      cs_hi = f1 * cs_hi + i1 * g1;
      float h2lo = o0 * tanh_f(cs_lo);
      float h2hi = o1 * tanh_f(cs_hi);
      h2v hp = h2v{(_Float16)h2lo, (_Float16)h2hi};
      hbuf2[row][kk] = __builtin_bit_cast(unsigned, hp);
      float p = h2lo * wl_lo + h2hi * wl_hi;
#pragma unroll
      for (int s = 1; s < 64; s <<= 1) p += __shfl_xor(p, s, 64);
      if (kk == 0) redbuf[row] = p;
    }
    __syncthreads();

    // ---- phase 5: w_hh2 @ h2new (for next step), store output
    {
      int hv2a = (int)hbuf2[0][lane];
      int hv2b = (int)hbuf2[1][lane];
      p2ha = 0.f; p2hb = 0.f;
#pragma unroll
      for (int i = 0; i < 64; ++i) {
        int qa = __builtin_amdgcn_readlane(hv2a, i);
        int qb = __builtin_amdgcn_readlane(hv2b, i);
        p2ha = dot2acc(__builtin_bit_cast(h2v, qa), w2h[i], p2ha);
        p2hb = dot2acc(__builtin_bit_cast(h2v, qb), w2h[i], p2hb);
      }
      if (tid < 2) {
        out[(r0 + tid) * LSTM_L + t] = redbuf[tid] + blv;
      }
    }
  }
}

extern "C" void kernel_launch(void* const* d_in, const int* in_sizes, int n_in,
                              void* d_out, int out_size, void* d_ws, size_t ws_size,
                              hipStream_t stream) {
  const float* x     = (const float*)d_in[0];
  const float* w_ih1 = (const float*)d_in[1];
  const float* w_hh1 = (const float*)d_in[2];
  const float* b_ih1 = (const float*)d_in[3];
  const float* b_hh1 = (const float*)d_in[4];
  const float* w_ih2 = (const float*)d_in[5];
  const float* w_hh2 = (const float*)d_in[6];
  const float* b_ih2 = (const float*)d_in[7];
  const float* b_hh2 = (const float*)d_in[8];
  const float* w_lin = (const float*)d_in[9];
  const float* b_lin = (const float*)d_in[10];

  lstm_fused<<<LSTM_B / 2, 512, 0, stream>>>(
      x, w_ih1, w_hh1, b_ih1, b_hh1, w_ih2, w_hh2, b_ih2, b_hh2,
      w_lin, b_lin, (float*)d_out);
}

// Round 4
// 2774.043 us; speedup vs baseline: 1.8886x; 1.8886x over previous
//
#include <hip/hip_runtime.h>

#define B_ 512
#define L_ 1000
#define H_ 128
#define G_ 512  // 4*H

typedef _Float16 v8h __attribute__((ext_vector_type(8)));
typedef _Float16 h2t __attribute__((ext_vector_type(2)));
typedef float v4f __attribute__((ext_vector_type(4)));

__device__ __forceinline__ float sigmoid_f(float x) {
  return __builtin_amdgcn_rcpf(1.0f + __builtin_amdgcn_exp2f(-1.4426950408889634f * x));
}
__device__ __forceinline__ float tanh_f(float x) {
  return 1.0f - 2.0f * __builtin_amdgcn_rcpf(1.0f + __builtin_amdgcn_exp2f(2.8853900817779268f * x));
}

// 256 blocks x 1024 threads (16 waves). One block = one CU owns 2 batch rows.
// Weights live as f16 MFMA A-fragments distributed across each wave:
// wave w owns gates [32w, 32w+32) of w_hh1, w_ih2, w_hh2 = 3 x 2 Mtiles x
// 4 Ktiles x 4 dwords = 96 VGPRs/thread -> fits the compiler's 128-VGPR
// default (rounds 1-3: 192-dword design spilled, un-fixable via attributes).
// h vectors live in LDS as f16; B-fragments are broadcast ds_read_b128.
// Gate pre-activations go to LDS in MFMA C-layout (n=lane&15 is batch row,
// m=quad*4+reg is gate-within-tile); waves 0-1 do the layer-1 c/h update,
// waves 2-3 layer-2 (one update wave per SIMD), carrying c-state in regs.
__global__ __launch_bounds__(1024) void lstm_mfma(
    const float* __restrict__ x,
    const float* __restrict__ w_ih1,
    const float* __restrict__ w_hh1,
    const float* __restrict__ b_ih1,
    const float* __restrict__ b_hh1,
    const float* __restrict__ w_ih2,
    const float* __restrict__ w_hh2,
    const float* __restrict__ b_ih2,
    const float* __restrict__ b_hh2,
    const float* __restrict__ w_lin,
    const float* __restrict__ b_lin,
    float* __restrict__ out)
{
  __shared__ __align__(16) float     xlds[2][L_];   // block's 2 x-rows
  __shared__ __align__(16) float     gbuf[2][G_];   // raw gates [row][gate]
  __shared__ __align__(16) _Float16  h1buf[2][H_];  // h1 as f16
  __shared__ __align__(16) _Float16  h2buf[2][H_];  // h2 as f16
  __shared__ __align__(16) float     wxb[G_];       // w_ih1 column
  __shared__ __align__(16) float     bbb1[G_];      // b_ih1+b_hh1
  __shared__ __align__(16) float     bbb2[G_];      // b_ih2+b_hh2
  __shared__ __align__(16) float     wlb[H_];       // w_lin row

  const int tid   = threadIdx.x;
  const int wv    = tid >> 6;
  const int lane  = tid & 63;
  const int quad  = lane >> 4;
  const int m15   = lane & 15;
  const int nrow  = m15 & 1;   // batch row this lane's B/C column maps to
  const int r0    = blockIdx.x * 2;
  const int gbase = wv * 32;

  // ---- one-time staging ----
  for (int i = tid; i < 2 * L_; i += 1024) ((float*)xlds)[i] = x[r0 * L_ + i];
  if (tid < G_) {
    wxb[tid]  = w_ih1[tid];
    bbb1[tid] = b_ih1[tid] + b_hh1[tid];
    bbb2[tid] = b_ih2[tid] + b_hh2[tid];
  }
  if (tid < H_) wlb[tid] = w_lin[tid];
  if (tid < 128) { ((unsigned*)h1buf)[tid] = 0u; ((unsigned*)h2buf)[tid] = 0u; }

  // ---- per-wave weight A-fragments (f16), full K per wave ----
  // A[m][k]: m = lane&15 (gate within tile), k = quad*8 + j
  v8h A1[2][4], A2i[2][4], A2h[2][4];
#pragma unroll
  for (int mt = 0; mt < 2; ++mt) {
    const int grow = (gbase + mt * 16 + m15) * H_;
#pragma unroll
    for (int kt = 0; kt < 4; ++kt) {
      const int koff = kt * 32 + quad * 8;
      float4 a, b;
      a = *(const float4*)(w_hh1 + grow + koff);
      b = *(const float4*)(w_hh1 + grow + koff + 4);
      A1[mt][kt] = v8h{(_Float16)a.x, (_Float16)a.y, (_Float16)a.z, (_Float16)a.w,
                       (_Float16)b.x, (_Float16)b.y, (_Float16)b.z, (_Float16)b.w};
      a = *(const float4*)(w_ih2 + grow + koff);
      b = *(const float4*)(w_ih2 + grow + koff + 4);
      A2i[mt][kt] = v8h{(_Float16)a.x, (_Float16)a.y, (_Float16)a.z, (_Float16)a.w,
                        (_Float16)b.x, (_Float16)b.y, (_Float16)b.z, (_Float16)b.w};
      a = *(const float4*)(w_hh2 + grow + koff);
      b = *(const float4*)(w_hh2 + grow + koff + 4);
      A2h[mt][kt] = v8h{(_Float16)a.x, (_Float16)a.y, (_Float16)a.z, (_Float16)a.w,
                        (_Float16)b.x, (_Float16)b.y, (_Float16)b.z, (_Float16)b.w};
    }
  }

  float c1s0 = 0.f, c1s1 = 0.f;  // layer-1 cell state (threads 0..127, 2 hids)
  float c2s0 = 0.f, c2s1 = 0.f;  // layer-2 cell state (threads 128..255)
  const float blv = b_lin[0];

  __syncthreads();

  for (int t = 0; t < L_; ++t) {
    // ---- P1 compute: raw g1 = w_hh1 @ h1_prev  (x-term/bias in update) ----
    {
      v4f acc0 = {0.f, 0.f, 0.f, 0.f}, acc1 = {0.f, 0.f, 0.f, 0.f};
#pragma unroll
      for (int kt = 0; kt < 4; ++kt) {
        v8h b = *(const v8h*)(&h1buf[nrow][kt * 32 + quad * 8]);
        acc0 = __builtin_amdgcn_mfma_f32_16x16x32_f16(A1[0][kt], b, acc0, 0, 0, 0);
        acc1 = __builtin_amdgcn_mfma_f32_16x16x32_f16(A1[1][kt], b, acc1, 0, 0, 0);
      }
      if (m15 < 2) {
        *(v4f*)(&gbuf[m15][gbase + quad * 4])      = acc0;
        *(v4f*)(&gbuf[m15][gbase + 16 + quad * 4]) = acc1;
      }
    }
    __syncthreads();

    // ---- P1 update: waves 0,1 (wave = batch row), thread owns hids 2l,2l+1
    if (tid < 128) {
      const int row = tid >> 6;
      const int e   = lane * 2;
      const float xv = xlds[row][t];
      float2 gi = *(const float2*)&gbuf[row][e];
      float2 gf = *(const float2*)&gbuf[row][128 + e];
      float2 gg = *(const float2*)&gbuf[row][256 + e];
      float2 go = *(const float2*)&gbuf[row][384 + e];
      float2 wxi = *(const float2*)&wxb[e],       bi = *(const float2*)&bbb1[e];
      float2 wxf = *(const float2*)&wxb[128 + e], bf = *(const float2*)&bbb1[128 + e];
      float2 wxg = *(const float2*)&wxb[256 + e], bg = *(const float2*)&bbb1[256 + e];
      float2 wxo = *(const float2*)&wxb[384 + e], bo = *(const float2*)&bbb1[384 + e];
      float i0 = sigmoid_f(gi.x + wxi.x * xv + bi.x);
      float i1 = sigmoid_f(gi.y + wxi.y * xv + bi.y);
      float f0 = sigmoid_f(gf.x + wxf.x * xv + bf.x);
      float f1 = sigmoid_f(gf.y + wxf.y * xv + bf.y);
      float g0 = tanh_f(gg.x + wxg.x * xv + bg.x);
      float g1 = tanh_f(gg.y + wxg.y * xv + bg.y);
      float o0 = sigmoid_f(go.x + wxo.x * xv + bo.x);
      float o1 = sigmoid_f(go.y + wxo.y * xv + bo.y);
      c1s0 = f0 * c1s0 + i0 * g0;
      c1s1 = f1 * c1s1 + i1 * g1;
      h2t hp = h2t{(_Float16)(o0 * tanh_f(c1s0)), (_Float16)(o1 * tanh_f(c1s1))};
      *(h2t*)(&h1buf[row][e]) = hp;
    }
    __syncthreads();

    // ---- P2 compute: raw g2 = w_ih2 @ h1 + w_hh2 @ h2_prev ----
    {
      v4f acc0 = {0.f, 0.f, 0.f, 0.f}, acc1 = {0.f, 0.f, 0.f, 0.f};
#pragma unroll
      for (int kt = 0; kt < 4; ++kt) {
        v8h b = *(const v8h*)(&h1buf[nrow][kt * 32 + quad * 8]);
        acc0 = __builtin_amdgcn_mfma_f32_16x16x32_f16(A2i[0][kt], b, acc0, 0, 0, 0);
        acc1 = __builtin_amdgcn_mfma_f32_16x16x32_f16(A2i[1][kt], b, acc1, 0, 0, 0);
      }
#pragma unroll
      for (int kt = 0; kt < 4; ++kt) {
        v8h b = *(const v8h*)(&h2buf[nrow][kt * 32 + quad * 8]);
        acc0 = __builtin_amdgcn_mfma_f32_16x16x32_f16(A2h[0][kt], b, acc0, 0, 0, 0);
        acc1 = __builtin_amdgcn_mfma_f32_16x16x32_f16(A2h[1][kt], b, acc1, 0, 0, 0);
      }
      if (m15 < 2) {
        *(v4f*)(&gbuf[m15][gbase + quad * 4])      = acc0;
        *(v4f*)(&gbuf[m15][gbase + 16 + quad * 4]) = acc1;
      }
    }
    __syncthreads();

    // ---- P2 update: waves 2,3; also w_lin reduction + output store ----
    if (tid >= 128 && tid < 256) {
      const int row = (tid >> 6) & 1;
      const int e   = lane * 2;
      float2 gi = *(const float2*)&gbuf[row][e];
      float2 gf = *(const float2*)&gbuf[row][128 + e];
      float2 gg = *(const float2*)&gbuf[row][256 + e];
      float2 go = *(const float2*)&gbuf[row][384 + e];
      float2 bi = *(const float2*)&bbb2[e];
      float2 bf = *(const float2*)&bbb2[128 + e];
      float2 bg = *(const float2*)&bbb2[256 + e];
      float2 bo = *(const float2*)&bbb2[384 + e];
      float i0 = sigmoid_f(gi.x + bi.x);
      float i1 = sigmoid_f(gi.y + bi.y);
      float f0 = sigmoid_f(gf.x + bf.x);
      float f1 = sigmoid_f(gf.y + bf.y);
      float g0 = tanh_f(gg.x + bg.x);
      float g1 = tanh_f(gg.y + bg.y);
      float o0 = sigmoid_f(go.x + bo.x);
      float o1 = sigmoid_f(go.y + bo.y);
      c2s0 = f0 * c2s0 + i0 * g0;
      c2s1 = f1 * c2s1 + i1 * g1;
      float h0 = o0 * tanh_f(c2s0);
      float h1 = o1 * tanh_f(c2s1);
      *(h2t*)(&h2buf[row][e]) = h2t{(_Float16)h0, (_Float16)h1};
      float2 wl = *(const float2*)&wlb[e];
      float p = h0 * wl.x + h1 * wl.y;
#pragma unroll
      for (int s = 1; s < 64; s <<= 1) p += __shfl_xor(p, s, 64);
      if (lane == 0) out[(r0 + row) * L_ + t] = p + blv;
    }
    __syncthreads();
  }
}

extern "C" void kernel_launch(void* const* d_in, const int* in_sizes, int n_in,
                              void* d_out, int out_size, void* d_ws, size_t ws_size,
                              hipStream_t stream) {
  const float* x     = (const float*)d_in[0];
  const float* w_ih1 = (const float*)d_in[1];
  const float* w_hh1 = (const float*)d_in[2];
  const float* b_ih1 = (const float*)d_in[3];
  const float* b_hh1 = (const float*)d_in[4];
  const float* w_ih2 = (const float*)d_in[5];
  const float* w_hh2 = (const float*)d_in[6];
  const float* b_ih2 = (const float*)d_in[7];
  const float* b_hh2 = (const float*)d_in[8];
  const float* w_lin = (const float*)d_in[9];
  const float* b_lin = (const float*)d_in[10];

  lstm_mfma<<<B_ / 2, 1024, 0, stream>>>(
      x, w_ih1, w_hh1, b_ih1, b_hh1, w_ih2, w_hh2, b_ih2, b_hh2,
      w_lin, b_lin, (float*)d_out);
}